// Round 1
// baseline (214.160 us; speedup 1.0000x reference)
//
#include <hip/hip_runtime.h>
#include <math.h>

// Problem constants: [N, L, H, D] = [4, 8192, 8, 64], Dv = 64, fp32 in/out.
#define N_   4
#define L_   8192
#define H_   8
#define D_   64
#define NH_  32            // N*H
#define CHK  64            // chunk length
#define NC_  (L_ / CHK)    // 128 chunks
#define ROWF 512           // H_*D_ floats between consecutive l
#define EPSF 1e-6f

// elu(x)+1  (jax.nn.elu alpha=1)
__device__ __forceinline__ float fmap(float x) { return x > 0.f ? x + 1.f : __expf(x); }

// XOR swizzle of the float4 column slot to break stride-64 bank conflicts.
__device__ __forceinline__ int swz(int r) { return (r >> 2) & 15; }
__device__ __forceinline__ int lidx4(int r, int c4) { return r * 64 + (((c4) ^ swz(r)) << 2); }
// scalar element (r, c) in a swizzled [rows][64] tile
__device__ __forceinline__ int lidx1(int r, int c) { return r * 64 + ((((c) >> 2) ^ swz(r)) << 2) + ((c) & 3); }

__device__ __forceinline__ void mac4(const float4& a, const float4& b0, const float4& b1,
                                     const float4& b2, const float4& b3, float4& o) {
  o.x = fmaf(a.x, b0.x, fmaf(a.y, b1.x, fmaf(a.z, b2.x, fmaf(a.w, b3.x, o.x))));
  o.y = fmaf(a.x, b0.y, fmaf(a.y, b1.y, fmaf(a.z, b2.y, fmaf(a.w, b3.y, o.y))));
  o.z = fmaf(a.x, b0.z, fmaf(a.y, b1.z, fmaf(a.z, b2.z, fmaf(a.w, b3.z, o.z))));
  o.w = fmaf(a.x, b0.w, fmaf(a.y, b1.w, fmaf(a.z, b2.w, fmaf(a.w, b3.w, o.w))));
}

// ---------------- Kernel 1: per-chunk K^T V sums and K column-sums ----------------
__global__ __launch_bounds__(256) void k_chunk_sums(const float* __restrict__ keys,
                                                    const float* __restrict__ values,
                                                    float* __restrict__ Sws,
                                                    float* __restrict__ Kws) {
  __shared__ float Ks[CHK * 64];
  __shared__ float Vs[CHK * 64];
  const int bid = blockIdx.x;          // nh*NC_ + c
  const int nh = bid / NC_, c = bid % NC_;
  const int n = nh / H_, h = nh % H_;
  const int tid = threadIdx.x;
  const int rr = tid >> 4, c4 = tid & 15;

  for (int r = rr; r < CHK; r += 16) {
    const int l = c * CHK + r;
    const size_t g = (size_t)(n * L_ + l) * ROWF + h * 64 + (c4 << 2);
    float4 k = *(const float4*)&keys[g];
    k.x = fmap(k.x); k.y = fmap(k.y); k.z = fmap(k.z); k.w = fmap(k.w);
    *(float4*)&Ks[lidx4(r, c4)] = k;
    *(float4*)&Vs[lidx4(r, c4)] = *(const float4*)&values[g];
  }
  __syncthreads();

  const int ty = rr, tx = c4;          // d-tile, e-tile
  float acc[4][4];
#pragma unroll
  for (int i = 0; i < 4; ++i)
#pragma unroll
    for (int j = 0; j < 4; ++j) acc[i][j] = 0.f;

  for (int s = 0; s < CHK; ++s) {
    const float4 k4 = *(const float4*)&Ks[lidx4(s, ty)];
    const float4 v4 = *(const float4*)&Vs[lidx4(s, tx)];
    const float ka[4] = {k4.x, k4.y, k4.z, k4.w};
    const float va[4] = {v4.x, v4.y, v4.z, v4.w};
#pragma unroll
    for (int i = 0; i < 4; ++i)
#pragma unroll
      for (int j = 0; j < 4; ++j) acc[i][j] = fmaf(ka[i], va[j], acc[i][j]);
  }

  float* Sg = Sws + (size_t)bid * 4096;
#pragma unroll
  for (int i = 0; i < 4; ++i)
    *(float4*)&Sg[(ty * 4 + i) * 64 + (tx << 2)] =
        make_float4(acc[i][0], acc[i][1], acc[i][2], acc[i][3]);

  if (tid < 64) {
    float s = 0.f;
    for (int ss = 0; ss < CHK; ++ss) s += Ks[lidx1(ss, tid)];
    Kws[(size_t)bid * 64 + tid] = s;
  }
}

// ---------------- Kernel 2: exclusive prefix over chunks (in place) ----------------
__global__ __launch_bounds__(256) void k_prefix(float* __restrict__ Sws, float* __restrict__ Kws) {
  const int tid = threadIdx.x;
  if (blockIdx.x < 512) {
    const int gid = blockIdx.x * 256 + tid;       // 0 .. 131071
    const int nh = gid >> 12, de = gid & 4095;
    float* p = Sws + (size_t)nh * NC_ * 4096 + de;
    float run = 0.f;
    for (int cc = 0; cc < NC_; ++cc) {
      const float x = p[(size_t)cc * 4096];
      p[(size_t)cc * 4096] = run;
      run += x;
    }
  } else {
    const int gid = (blockIdx.x - 512) * 256 + tid;  // 0 .. 2047
    const int nh = gid >> 6, d = gid & 63;
    float* p = Kws + (size_t)nh * NC_ * 64 + d;
    float run = 0.f;
    for (int cc = 0; cc < NC_; ++cc) {
      const float x = p[cc * 64];
      p[cc * 64] = run;
      run += x;
    }
  }
}

// ---------------- Kernel 3: per-chunk attention + inter-chunk term + normalizer ----------------
__global__ __launch_bounds__(256) void k_output(const float* __restrict__ queries,
                                                const float* __restrict__ keys,
                                                const float* __restrict__ values,
                                                const float* __restrict__ Sws,
                                                const float* __restrict__ Kws,
                                                float* __restrict__ out) {
  __shared__ float Qs[CHK * 64];
  __shared__ float Bs[CHK * 64];   // K first, then V
  __shared__ float At[CHK * 64];   // attn 64x64, masked
  __shared__ float Ss[64 * 64];    // S prefix
  __shared__ float kpre[64];
  __shared__ float zinv[CHK];

  const int bid = blockIdx.x;
  const int nh = bid / NC_, c = bid % NC_;
  const int n = nh / H_, h = nh % H_;
  const int tid = threadIdx.x;
  const int rr = tid >> 4, c4 = tid & 15;

  for (int r = rr; r < CHK; r += 16) {
    const int l = c * CHK + r;
    const size_t g = (size_t)(n * L_ + l) * ROWF + h * 64 + (c4 << 2);
    float4 q = *(const float4*)&queries[g];
    float4 k = *(const float4*)&keys[g];
    q.x = fmap(q.x); q.y = fmap(q.y); q.z = fmap(q.z); q.w = fmap(q.w);
    k.x = fmap(k.x); k.y = fmap(k.y); k.z = fmap(k.z); k.w = fmap(k.w);
    *(float4*)&Qs[lidx4(r, c4)] = q;
    *(float4*)&Bs[lidx4(r, c4)] = k;
  }
  if (tid < 16)
    *(float4*)&kpre[tid << 2] = *(const float4*)&Kws[(size_t)bid * 64 + (tid << 2)];
  __syncthreads();

  const int ty = rr, tx = c4;
  const int t0 = ty * 4, s0 = tx * 4;

  // ---- phase A: attn = tril(Q K^T) ----
  float acc[4][4];
#pragma unroll
  for (int i = 0; i < 4; ++i)
#pragma unroll
    for (int j = 0; j < 4; ++j) acc[i][j] = 0.f;

  for (int d4 = 0; d4 < 16; ++d4) {
    float4 q[4], k[4];
#pragma unroll
    for (int i = 0; i < 4; ++i) q[i] = *(const float4*)&Qs[(t0 + i) * 64 + ((d4 ^ swz(t0 + i)) << 2)];
#pragma unroll
    for (int j = 0; j < 4; ++j) k[j] = *(const float4*)&Bs[(s0 + j) * 64 + ((d4 ^ swz(s0 + j)) << 2)];
#pragma unroll
    for (int i = 0; i < 4; ++i)
#pragma unroll
      for (int j = 0; j < 4; ++j)
        acc[i][j] = fmaf(q[i].x, k[j].x,
                    fmaf(q[i].y, k[j].y,
                    fmaf(q[i].z, k[j].z,
                    fmaf(q[i].w, k[j].w, acc[i][j]))));
  }
#pragma unroll
  for (int i = 0; i < 4; ++i) {
    const int t = t0 + i;
    float4 m;
    m.x = (s0 + 0 <= t) ? acc[i][0] : 0.f;
    m.y = (s0 + 1 <= t) ? acc[i][1] : 0.f;
    m.z = (s0 + 2 <= t) ? acc[i][2] : 0.f;
    m.w = (s0 + 3 <= t) ? acc[i][3] : 0.f;
    *(float4*)&At[t * 64 + ((tx ^ swz(t)) << 2)] = m;
  }
  __syncthreads();

  // ---- overlap: load V into Bs, load S prefix; compute zinv on wave 0 ----
  for (int r = rr; r < CHK; r += 16) {
    const int l = c * CHK + r;
    const size_t g = (size_t)(n * L_ + l) * ROWF + h * 64 + (c4 << 2);
    *(float4*)&Bs[lidx4(r, c4)] = *(const float4*)&values[g];
  }
  {
    const float* Sg = Sws + (size_t)bid * 4096;
    for (int idx = tid; idx < 1024; idx += 256) {
      const int r = idx >> 4, cc4 = idx & 15;
      *(float4*)&Ss[lidx4(r, cc4)] = *(const float4*)&Sg[r * 64 + (cc4 << 2)];
    }
  }
  if (tid < CHK) {
    const int t = tid;
    float den = EPSF;
    for (int s2 = 0; s2 < CHK; ++s2) den += At[lidx1(t, s2)];          // masked rowsum (incl diag)
    for (int d = 0; d < 64; ++d) den += Qs[lidx1(t, d)] * kpre[d];      // inter-chunk part
    zinv[t] = 1.f / den;
  }
  __syncthreads();

  // ---- phase B: out = attn * V + Q * Sprefix ----
  float4 o[4];
#pragma unroll
  for (int i = 0; i < 4; ++i) o[i] = make_float4(0.f, 0.f, 0.f, 0.f);

  for (int s4 = 0; s4 < 16; ++s4) {
    float4 b[4];
#pragma unroll
    for (int j = 0; j < 4; ++j) {
      const int r = s4 * 4 + j;
      b[j] = *(const float4*)&Bs[r * 64 + ((tx ^ swz(r)) << 2)];
    }
#pragma unroll
    for (int i = 0; i < 4; ++i) {
      const float4 a = *(const float4*)&At[(t0 + i) * 64 + ((s4 ^ swz(t0 + i)) << 2)];
      mac4(a, b[0], b[1], b[2], b[3], o[i]);
    }
  }
  for (int d4 = 0; d4 < 16; ++d4) {
    float4 b[4];
#pragma unroll
    for (int j = 0; j < 4; ++j) {
      const int r = d4 * 4 + j;
      b[j] = *(const float4*)&Ss[r * 64 + ((tx ^ swz(r)) << 2)];
    }
#pragma unroll
    for (int i = 0; i < 4; ++i) {
      const float4 a = *(const float4*)&Qs[(t0 + i) * 64 + ((d4 ^ swz(t0 + i)) << 2)];
      mac4(a, b[0], b[1], b[2], b[3], o[i]);
    }
  }

#pragma unroll
  for (int i = 0; i < 4; ++i) {
    const int t = t0 + i;
    const int l = c * CHK + t;
    const float z = zinv[t];
    float4 r;
    r.x = o[i].x * z; r.y = o[i].y * z; r.z = o[i].z * z; r.w = o[i].w * z;
    *(float4*)&out[(size_t)(n * L_ + l) * ROWF + h * 64 + (tx << 2)] = r;
  }
}

extern "C" void kernel_launch(void* const* d_in, const int* in_sizes, int n_in,
                              void* d_out, int out_size, void* d_ws, size_t ws_size,
                              hipStream_t stream) {
  const float* queries = (const float*)d_in[0];
  const float* keys    = (const float*)d_in[1];
  const float* values  = (const float*)d_in[2];
  float* out = (float*)d_out;

  // workspace: S chunk sums [NH_*NC_][64][64] then ksum [NH_*NC_][64]
  const size_t s_elems = (size_t)NH_ * NC_ * 4096;
  const size_t k_elems = (size_t)NH_ * NC_ * 64;
  if (ws_size < (s_elems + k_elems) * sizeof(float)) return;  // insufficient scratch
  float* Sws = (float*)d_ws;
  float* Kws = Sws + s_elems;

  hipLaunchKernelGGL(k_chunk_sums, dim3(NH_ * NC_), dim3(256), 0, stream, keys, values, Sws, Kws);
  hipLaunchKernelGGL(k_prefix, dim3(512 + 8), dim3(256), 0, stream, Sws, Kws);
  hipLaunchKernelGGL(k_output, dim3(NH_ * NC_), dim3(256), 0, stream,
                     queries, keys, values, Sws, Kws, out);
}

// Round 2
// 124.057 us; speedup vs baseline: 1.7263x; 1.7263x over previous
//
#include <hip/hip_runtime.h>
#include <math.h>

// Problem constants: [N, L, H, D] = [4, 8192, 8, 64], Dv = 64, fp32 in/out.
#define N_   4
#define L_   8192
#define H_   8
#define NH_  32            // N*H
#define CHK  64            // chunk length
#define NC_  (L_ / CHK)    // 128 chunks
#define ROWF 512           // H_*D_ floats between consecutive l
#define EPSF 1e-6f

typedef __attribute__((ext_vector_type(8))) short bf16x8;   // 8 bf16 = 4 VGPRs
typedef __attribute__((ext_vector_type(4))) float f32x4;
typedef __attribute__((ext_vector_type(4))) unsigned short us4;

__device__ __forceinline__ float fmap(float x) { return x > 0.f ? x + 1.f : __expf(x); }

__device__ __forceinline__ unsigned short f2bf(float x) {
  unsigned u = __float_as_uint(x);
  u += 0x7FFFu + ((u >> 16) & 1u);       // round-to-nearest-even
  return (unsigned short)(u >> 16);
}
__device__ __forceinline__ float bf2f(unsigned short u) {
  return __uint_as_float(((unsigned)u) << 16);
}

// Swizzled ushort index into a row-major [64] bf16 tile (row stride 128 B).
// XOR of col bits 3..5 with row&7 — bijective per row, keeps 8-groups and
// 4-groups contiguous, kills the stride-128B bank conflict (G4).
__device__ __forceinline__ int sidx(int row, int col) {
  return row * 64 + (col ^ ((row & 7) << 3));
}

__device__ __forceinline__ f32x4 MFMA(bf16x8 a, bf16x8 b, f32x4 c) {
  return __builtin_amdgcn_mfma_f32_16x16x32_bf16(a, b, c, 0, 0, 0);
}

// ---------------- Kernel 1: per-chunk S^T_c = V^T K (64x64) and ksum ----------------
__global__ __launch_bounds__(256) void k_chunk_sums(const float* __restrict__ keys,
                                                    const float* __restrict__ values,
                                                    float* __restrict__ Sws,
                                                    float* __restrict__ Kws) {
  __shared__ unsigned short Kt[64 * 64];  // K^T [d][s]  (fmap applied)
  __shared__ unsigned short Vt[64 * 64];  // V^T [e][s]
  const int bid = blockIdx.x;             // nh*NC_ + c
  const int nh = bid / NC_, c = bid % NC_;
  const int n = nh / H_, h = nh % H_;
  const int tid = threadIdx.x;
  const int lane = tid & 63;
  const int wv = tid >> 6;

  // transposed staging: thread owns column d, 4 reps of 4 rows
  {
    const int d = tid & 63, sg = tid >> 6;
    const size_t gbase = ((size_t)(n * L_ + c * CHK)) * ROWF + h * 64 + d;
    for (int rep = 0; rep < 4; ++rep) {
      const int s0 = (sg * 4 + rep) * 4;
      us4 wk, wvv;
#pragma unroll
      for (int j = 0; j < 4; ++j) {
        const size_t g = gbase + (size_t)(s0 + j) * ROWF;
        wk[j]  = f2bf(fmap(keys[g]));
        wvv[j] = f2bf(values[g]);
      }
      *(us4*)&Kt[sidx(d, s0)] = wk;
      *(us4*)&Vt[sidx(d, s0)] = wvv;
    }
  }
  __syncthreads();

  // ksum[d] = sum_s K[s][d]  (row d of Kt)
  if (tid < 64) {
    float s = 0.f;
    for (int g8 = 0; g8 < 8; ++g8) {
      const int base = sidx(tid, g8 * 8);
#pragma unroll
      for (int j = 0; j < 8; ++j) s += bf2f(Kt[base + j]);
    }
    Kws[(size_t)bid * 64 + tid] = s;
  }

  // per-wave e-tile of S^T: rows e0..e0+15
  const int e0 = wv * 16;
  const int arow = e0 + (lane & 15);
  const int lg = lane >> 4;
  bf16x8 av0 = *(const bf16x8*)&Vt[sidx(arow, lg * 8)];
  bf16x8 av1 = *(const bf16x8*)&Vt[sidx(arow, (lg + 4) * 8)];
  float* Sg = Sws + (size_t)bid * 4096;
#pragma unroll
  for (int nt = 0; nt < 4; ++nt) {
    const int brow = nt * 16 + (lane & 15);
    f32x4 acc = {0.f, 0.f, 0.f, 0.f};
    acc = MFMA(av0, *(const bf16x8*)&Kt[sidx(brow, lg * 8)], acc);
    acc = MFMA(av1, *(const bf16x8*)&Kt[sidx(brow, (lg + 4) * 8)], acc);
    const int e = e0 + lg * 4;
    const int d = nt * 16 + (lane & 15);
#pragma unroll
    for (int r = 0; r < 4; ++r) Sg[(size_t)(e + r) * 64 + d] = acc[r];
  }
}

// ---------------- Kernel 2: exclusive prefix over chunks (in place, fp32) ----------------
__global__ __launch_bounds__(256) void k_prefix(float* __restrict__ Sws, float* __restrict__ Kws) {
  const int tid = threadIdx.x;
  if (blockIdx.x < 512) {
    const int gid = blockIdx.x * 256 + tid;          // 0 .. 131071
    const int nh = gid >> 12, de = gid & 4095;
    float* p = Sws + (size_t)nh * NC_ * 4096 + de;
    float run = 0.f;
    for (int cc = 0; cc < NC_; ++cc) {
      const float x = p[(size_t)cc * 4096];
      p[(size_t)cc * 4096] = run;
      run += x;
    }
  } else {
    const int gid = (blockIdx.x - 512) * 256 + tid;  // 0 .. 2047
    const int nh = gid >> 6, d = gid & 63;
    float* p = Kws + (size_t)nh * NC_ * 64 + d;
    float run = 0.f;
    for (int cc = 0; cc < NC_; ++cc) {
      const float x = p[cc * 64];
      p[cc * 64] = run;
      run += x;
    }
  }
}

// ---------------- Kernel 3: attn = tril(QK^T); out = (attn V + Q S) * zinv ----------------
__global__ __launch_bounds__(256) void k_output(const float* __restrict__ queries,
                                                const float* __restrict__ keys,
                                                const float* __restrict__ values,
                                                const float* __restrict__ Sws,
                                                const float* __restrict__ Kws,
                                                float* __restrict__ out) {
  __shared__ unsigned short Qs[64 * 64];  // Q row-major (fmap)
  __shared__ unsigned short Ks[64 * 64];  // K row-major (fmap); reused as attn tile
  __shared__ unsigned short Vt[64 * 64];  // V^T [e][s]
  __shared__ unsigned short St[64 * 64];  // S^T [e][d] prefix (bf16 from ws)
  __shared__ float kpre[64];
  __shared__ float zden[64];
  __shared__ float zinv[64];

  const int bid = blockIdx.x;
  const int nh = bid / NC_, c = bid % NC_;
  const int n = nh / H_, h = nh % H_;
  const int tid = threadIdx.x;
  const int lane = tid & 63;
  const int wv = tid >> 6;

  // row-major staging of Q, K (fmap+bf16) and S^T (ws fp32 -> bf16)
  {
    const int r = tid >> 4, c4 = (tid & 15) * 4;
    for (int rep = 0; rep < 4; ++rep) {
      const int row = r + rep * 16;
      const size_t g = ((size_t)(n * L_ + c * CHK + row)) * ROWF + h * 64 + c4;
      const float4 q = *(const float4*)&queries[g];
      const float4 k = *(const float4*)&keys[g];
      us4 uq, uk, us_;
      uq[0] = f2bf(fmap(q.x)); uq[1] = f2bf(fmap(q.y)); uq[2] = f2bf(fmap(q.z)); uq[3] = f2bf(fmap(q.w));
      uk[0] = f2bf(fmap(k.x)); uk[1] = f2bf(fmap(k.y)); uk[2] = f2bf(fmap(k.z)); uk[3] = f2bf(fmap(k.w));
      *(us4*)&Qs[sidx(row, c4)] = uq;
      *(us4*)&Ks[sidx(row, c4)] = uk;
      const float4 s4 = *(const float4*)&Sws[(size_t)bid * 4096 + row * 64 + c4];
      us_[0] = f2bf(s4.x); us_[1] = f2bf(s4.y); us_[2] = f2bf(s4.z); us_[3] = f2bf(s4.w);
      *(us4*)&St[sidx(row, c4)] = us_;
    }
  }
  // V transposed staging
  {
    const int d = tid & 63, sg = tid >> 6;
    const size_t gbase = ((size_t)(n * L_ + c * CHK)) * ROWF + h * 64 + d;
    for (int rep = 0; rep < 4; ++rep) {
      const int s0 = (sg * 4 + rep) * 4;
      us4 w;
#pragma unroll
      for (int j = 0; j < 4; ++j) w[j] = f2bf(values[gbase + (size_t)(s0 + j) * ROWF]);
      *(us4*)&Vt[sidx(d, s0)] = w;
    }
  }
  if (tid < 16) *(float4*)&kpre[tid * 4] = *(const float4*)&Kws[(size_t)bid * 64 + tid * 4];
  __syncthreads();

  const int t0w = wv * 16;
  const int lane15 = lane & 15;
  const int lg = lane >> 4;
  const int arow = t0w + lane15;

  // ---- phase A: attn = Q K^T  (wave's 16 rows x 64 cols) ----
  bf16x8 qf0 = *(const bf16x8*)&Qs[sidx(arow, lg * 8)];
  bf16x8 qf1 = *(const bf16x8*)&Qs[sidx(arow, (lg + 4) * 8)];
  f32x4 attC[4];
#pragma unroll
  for (int nt = 0; nt < 4; ++nt) {
    const int brow = nt * 16 + lane15;
    f32x4 a = {0.f, 0.f, 0.f, 0.f};
    a = MFMA(qf0, *(const bf16x8*)&Ks[sidx(brow, lg * 8)], a);
    a = MFMA(qf1, *(const bf16x8*)&Ks[sidx(brow, (lg + 4) * 8)], a);
    attC[nt] = a;
  }
  __syncthreads();  // all waves done reading Ks before it becomes the attn tile

  // ---- mask + fp32 rowsum (denominator) + bf16 attn write into Ks ----
  float rs[4] = {0.f, 0.f, 0.f, 0.f};
#pragma unroll
  for (int nt = 0; nt < 4; ++nt) {
#pragma unroll
    for (int r = 0; r < 4; ++r) {
      const int t = t0w + lg * 4 + r;
      const int s = nt * 16 + lane15;
      const float v = (s <= t) ? attC[nt][r] : 0.f;
      rs[r] += v;
      Ks[sidx(t, s)] = f2bf(v);
    }
  }
#pragma unroll
  for (int r = 0; r < 4; ++r) {
    float v = rs[r];
    v += __shfl_xor(v, 1);
    v += __shfl_xor(v, 2);
    v += __shfl_xor(v, 4);
    v += __shfl_xor(v, 8);
    if (lane15 == 0) zden[t0w + lg * 4 + r] = v;
  }
  __syncthreads();  // attn + zden visible

  // zinv on wave 0 (overlaps with phase B on waves 1-3)
  if (tid < 64) {
    float den = zden[tid] + EPSF;
    for (int g8 = 0; g8 < 8; ++g8) {
      const int base = sidx(tid, g8 * 8);
#pragma unroll
      for (int j = 0; j < 8; ++j) den += bf2f(Qs[base + j]) * kpre[g8 * 8 + j];
    }
    zinv[tid] = 1.f / den;
  }

  // ---- phase B: out = attn * V + Q * S ----
  bf16x8 af0 = *(const bf16x8*)&Ks[sidx(arow, lg * 8)];
  bf16x8 af1 = *(const bf16x8*)&Ks[sidx(arow, (lg + 4) * 8)];
  f32x4 oc[4];
#pragma unroll
  for (int nt = 0; nt < 4; ++nt) {
    const int brow = nt * 16 + lane15;
    f32x4 o = {0.f, 0.f, 0.f, 0.f};
    o = MFMA(af0, *(const bf16x8*)&Vt[sidx(brow, lg * 8)], o);
    o = MFMA(af1, *(const bf16x8*)&Vt[sidx(brow, (lg + 4) * 8)], o);
    o = MFMA(qf0, *(const bf16x8*)&St[sidx(brow, lg * 8)], o);
    o = MFMA(qf1, *(const bf16x8*)&St[sidx(brow, (lg + 4) * 8)], o);
    oc[nt] = o;
  }
  __syncthreads();  // zinv ready

  // ---- scale + store ----
#pragma unroll
  for (int nt = 0; nt < 4; ++nt) {
    const int e = nt * 16 + lane15;
#pragma unroll
    for (int r = 0; r < 4; ++r) {
      const int t = t0w + lg * 4 + r;
      out[((size_t)(n * L_ + c * CHK + t)) * ROWF + h * 64 + e] = oc[nt][r] * zinv[t];
    }
  }
}

extern "C" void kernel_launch(void* const* d_in, const int* in_sizes, int n_in,
                              void* d_out, int out_size, void* d_ws, size_t ws_size,
                              hipStream_t stream) {
  const float* queries = (const float*)d_in[0];
  const float* keys    = (const float*)d_in[1];
  const float* values  = (const float*)d_in[2];
  float* out = (float*)d_out;

  // workspace: S^T chunk sums [NH_*NC_][64][64] then ksum [NH_*NC_][64]
  const size_t s_elems = (size_t)NH_ * NC_ * 4096;
  const size_t k_elems = (size_t)NH_ * NC_ * 64;
  if (ws_size < (s_elems + k_elems) * sizeof(float)) return;
  float* Sws = (float*)d_ws;
  float* Kws = Sws + s_elems;

  hipLaunchKernelGGL(k_chunk_sums, dim3(NH_ * NC_), dim3(256), 0, stream, keys, values, Sws, Kws);
  hipLaunchKernelGGL(k_prefix, dim3(512 + 8), dim3(256), 0, stream, Sws, Kws);
  hipLaunchKernelGGL(k_output, dim3(NH_ * NC_), dim3(256), 0, stream,
                     queries, keys, values, Sws, Kws, out);
}